// Round 1
// baseline (868.063 us; speedup 1.0000x reference)
//
#include <hip/hip_runtime.h>
#include <hip/hip_fp16.h>

#define B_Q 1024
#define C_P 65536
#define D_DIM 1024
#define CAND_CAP 512
#define CAND_TARGET 32

typedef __bf16 bf16x8 __attribute__((ext_vector_type(8)));
typedef float f32x4 __attribute__((ext_vector_type(4)));

__device__ __forceinline__ unsigned short f2bf(float f) {
  unsigned int u = __float_as_uint(f);
  u += 0x7FFFu + ((u >> 16) & 1u);
  return (unsigned short)(u >> 16);
}

// ---------------- K1: row L2-normalize -> bf16 copy + inverse norms ----------
__global__ __launch_bounds__(256) void k_rownorm(
    const float* __restrict__ src, unsigned short* __restrict__ dst,
    float* __restrict__ inv_out, int nrows) {
  const int lane = threadIdx.x & 63;
  const int wave = threadIdx.x >> 6;
  const int row = blockIdx.x * 4 + wave;
  if (row >= nrows) return;
  const float4* r4 = (const float4*)(src + (size_t)row * D_DIM);
  float4 v[4];
  float ss = 0.f;
#pragma unroll
  for (int j = 0; j < 4; ++j) {
    v[j] = r4[lane + j * 64];
    ss += v[j].x * v[j].x + v[j].y * v[j].y + v[j].z * v[j].z + v[j].w * v[j].w;
  }
#pragma unroll
  for (int off = 32; off; off >>= 1) ss += __shfl_xor(ss, off);
  const float inv = 1.0f / fmaxf(sqrtf(ss), 1e-8f);
  if (lane == 0) inv_out[row] = inv;
  ushort4* d4 = (ushort4*)(dst + (size_t)row * D_DIM);
#pragma unroll
  for (int j = 0; j < 4; ++j) {
    ushort4 h;
    h.x = f2bf(v[j].x * inv);
    h.y = f2bf(v[j].y * inv);
    h.z = f2bf(v[j].z * inv);
    h.w = f2bf(v[j].w * inv);
    d4[lane + j * 64] = h;
  }
}

// ---------------- K2: bf16 GEMM  sims[b,c] = qn[b,:] . pn[c,:]  (fp16 out) ---
__global__ __launch_bounds__(256) void k_gemm(
    const unsigned short* __restrict__ qnh,
    const unsigned short* __restrict__ pnh,
    __half* __restrict__ sims) {
  constexpr int LDT = 72;  // 64 + 8 pad -> 144B row stride, 2-way banking (free)
  __shared__ unsigned short As[128 * LDT];
  __shared__ unsigned short Bs[128 * LDT];
  const int tid = threadIdx.x;
  const int lane = tid & 63;
  const int wave = tid >> 6;
  const int wr = wave >> 1, wc = wave & 1;
  const int bCol = blockIdx.x * 128;  // pattern block
  const int bRow = blockIdx.y * 128;  // query block

  const int srow = tid >> 3;        // 0..31
  const int scol = (tid & 7) * 8;   // element offset within 64-wide K window

  const unsigned short* Ag = qnh + (size_t)(bRow + srow) * D_DIM + scol;
  const unsigned short* Bg = pnh + (size_t)(bCol + srow) * D_DIM + scol;

  uint4 ra[4], rb[4];
#pragma unroll
  for (int i = 0; i < 4; ++i) {
    ra[i] = *(const uint4*)(Ag + (size_t)i * 32 * D_DIM);
    rb[i] = *(const uint4*)(Bg + (size_t)i * 32 * D_DIM);
  }

  f32x4 zv = {0.f, 0.f, 0.f, 0.f};
  f32x4 acc[4][4];
#pragma unroll
  for (int m = 0; m < 4; ++m)
#pragma unroll
    for (int n = 0; n < 4; ++n) acc[m][n] = zv;

  for (int t = 0; t < 16; ++t) {
    __syncthreads();
#pragma unroll
    for (int i = 0; i < 4; ++i) {
      *(uint4*)&As[(i * 32 + srow) * LDT + scol] = ra[i];
      *(uint4*)&Bs[(i * 32 + srow) * LDT + scol] = rb[i];
    }
    __syncthreads();
    if (t < 15) {
#pragma unroll
      for (int i = 0; i < 4; ++i) {
        ra[i] = *(const uint4*)(Ag + (size_t)i * 32 * D_DIM + (size_t)(t + 1) * 64);
        rb[i] = *(const uint4*)(Bg + (size_t)i * 32 * D_DIM + (size_t)(t + 1) * 64);
      }
    }
#pragma unroll
    for (int kk = 0; kk < 2; ++kk) {
      bf16x8 af[4], bfr[4];
#pragma unroll
      for (int m = 0; m < 4; ++m) {
        uint4 ua = *(const uint4*)&As[(wr * 64 + m * 16 + (lane & 15)) * LDT + kk * 32 + (lane >> 4) * 8];
        uint4 ub = *(const uint4*)&Bs[(wc * 64 + m * 16 + (lane & 15)) * LDT + kk * 32 + (lane >> 4) * 8];
        af[m] = __builtin_bit_cast(bf16x8, ua);
        bfr[m] = __builtin_bit_cast(bf16x8, ub);
      }
#pragma unroll
      for (int m = 0; m < 4; ++m)
#pragma unroll
        for (int n = 0; n < 4; ++n)
          acc[m][n] = __builtin_amdgcn_mfma_f32_16x16x32_bf16(af[m], bfr[n], acc[m][n], 0, 0, 0);
    }
  }

  const int pcol0 = bCol + wc * 64 + (lane & 15);
  const int qrow0 = bRow + wr * 64 + ((lane >> 4) << 2);
#pragma unroll
  for (int m = 0; m < 4; ++m)
#pragma unroll
    for (int n = 0; n < 4; ++n)
#pragma unroll
      for (int r = 0; r < 4; ++r)
        sims[(size_t)(qrow0 + m * 16 + r) * C_P + (pcol0 + n * 16)] =
            __float2half(acc[m][n][r]);
}

// ---------------- K3: per-query adaptive top-candidate selection -------------
__device__ __forceinline__ unsigned int h2key(unsigned int h) {
  return (h & 0x8000u) ? (0xFFFFu ^ h) : (h | 0x8000u);
}

__global__ __launch_bounds__(256) void k_cand(
    const __half* __restrict__ sims, int* __restrict__ cand_idx,
    int* __restrict__ cand_cnt) {
  const int b = blockIdx.x;
  const int tid = threadIdx.x;
  __shared__ unsigned int hist[2048];
  __shared__ int s_cnt;
  __shared__ int s_thr;
  __shared__ int cbuf[CAND_CAP];
  for (int i = tid; i < 2048; i += 256) hist[i] = 0;
  if (tid == 0) s_cnt = 0;
  __syncthreads();
  const unsigned int* row = (const unsigned int*)(sims + (size_t)b * C_P);
  for (int i = tid; i < C_P / 2; i += 256) {
    unsigned int u = row[i];
    atomicAdd(&hist[h2key(u & 0xFFFFu) >> 5], 1u);
    atomicAdd(&hist[h2key(u >> 16) >> 5], 1u);
  }
  __syncthreads();
  if (tid < 64) {  // wave 0: descending chunked suffix scan for threshold bin
    const int lane = tid;
    int cum = 0, thr = -1;
    for (int base = 2048 - 64; base >= 0; base -= 64) {
      int v = (int)hist[base + lane];
      int s = v;
#pragma unroll
      for (int off = 1; off < 64; off <<= 1) {
        int t2 = __shfl_down(s, off);
        if (lane + off < 64) s += t2;
      }
      int total = __shfl(s, 0);
      if (cum + total >= CAND_TARGET) {
        unsigned long long mb = __ballot(cum + s >= CAND_TARGET);
        thr = base + (63 - __clzll(mb));
        break;
      }
      cum += total;
    }
    if (lane == 0) s_thr = thr;
  }
  __syncthreads();
  const unsigned int thrkey = ((unsigned int)s_thr) << 5;
  for (int i = tid; i < C_P / 2; i += 256) {
    unsigned int u = row[i];
    if (h2key(u & 0xFFFFu) >= thrkey) {
      int p = atomicAdd(&s_cnt, 1);
      if (p < CAND_CAP) cbuf[p] = i * 2;
    }
    if (h2key(u >> 16) >= thrkey) {
      int p = atomicAdd(&s_cnt, 1);
      if (p < CAND_CAP) cbuf[p] = i * 2 + 1;
    }
  }
  __syncthreads();
  int cnt = s_cnt;
  if (cnt > CAND_CAP) cnt = CAND_CAP;
  if (tid == 0) cand_cnt[b] = cnt;
  for (int i = tid; i < cnt; i += 256) cand_idx[b * CAND_CAP + i] = cbuf[i];
}

// ---------------- K4: f64 refine, exact top-16, softmax, outputs -------------
__global__ __launch_bounds__(256) void k_final(
    const float* __restrict__ qc, const float* __restrict__ pat,
    const float* __restrict__ comp, const float* __restrict__ invq,
    const float* __restrict__ invp, const int* __restrict__ cand_idx,
    const int* __restrict__ cand_cnt, float* __restrict__ out) {
  const int b = blockIdx.x;
  const int tid = threadIdx.x;
  const int lane = tid & 63;
  const int wave = tid >> 6;
  __shared__ float qs[1024];
  __shared__ double sv[CAND_CAP];
  __shared__ int ci[CAND_CAP];
  __shared__ int topi[16];
  __shared__ double tops[16];
  __shared__ float wgt[16];
  const int cnt = cand_cnt[b];
  for (int i = tid; i < cnt; i += 256) ci[i] = cand_idx[b * CAND_CAP + i];
  ((float4*)qs)[tid] = ((const float4*)(qc + (size_t)b * D_DIM))[tid];
  __syncthreads();
  const double sq = (double)invq[b];
  for (int i = wave; i < cnt; i += 4) {
    const float4* p4 = (const float4*)(pat + (size_t)ci[i] * D_DIM);
    const float4* q4 = (const float4*)qs;
    double acc = 0.0;
#pragma unroll
    for (int j = 0; j < 4; ++j) {
      float4 p = p4[lane + j * 64];
      float4 q = q4[lane + j * 64];
      acc += (double)p.x * q.x + (double)p.y * q.y + (double)p.z * q.z +
             (double)p.w * q.w;
    }
#pragma unroll
    for (int off = 32; off; off >>= 1) acc += __shfl_xor(acc, off);
    if (lane == 0) sv[i] = acc * sq * (double)invp[ci[i]];
  }
  __syncthreads();
  if (wave == 0) {
    for (int k = 0; k < 16; ++k) {
      double bs = -1e300;
      int bi = 0x7FFFFFFF, bslot = -1;
      for (int s = lane; s < cnt; s += 64) {
        double d = sv[s];
        int id = ci[s];
        if (d > bs || (d == bs && id < bi)) { bs = d; bi = id; bslot = s; }
      }
#pragma unroll
      for (int off = 32; off; off >>= 1) {
        double ds = __shfl_xor(bs, off);
        int di = __shfl_xor(bi, off);
        int dsl = __shfl_xor(bslot, off);
        if (ds > bs || (ds == bs && di < bi)) { bs = ds; bi = di; bslot = dsl; }
      }
      if (lane == 0) {
        topi[k] = bi;
        tops[k] = bs;
        if (bslot >= 0) sv[bslot] = -1e301;  // remove winner
      }
    }
    if (lane < 16) {
      float ts = (float)tops[lane];
      wgt[lane] = ts * (1.0f + comp[topi[lane]]);
    }
  }
  __syncthreads();
  if (tid == 0) {  // softmax over 16
    float m = wgt[0];
    for (int k = 1; k < 16; ++k) m = fmaxf(m, wgt[k]);
    float e[16];
    float ssum = 0.f;
    for (int k = 0; k < 16; ++k) {
      e[k] = expf(wgt[k] - m);
      ssum += e[k];
    }
    for (int k = 0; k < 16; ++k) wgt[k] = e[k] / ssum;
  }
  __syncthreads();
  float4 a4 = {0.f, 0.f, 0.f, 0.f};
  for (int k = 0; k < 16; ++k) {
    float4 pv = ((const float4*)(pat + (size_t)topi[k] * D_DIM))[tid];
    const float w = wgt[k];
    a4.x += w * pv.x;
    a4.y += w * pv.y;
    a4.z += w * pv.z;
    a4.w += w * pv.w;
  }
  ((float4*)(out + (size_t)b * D_DIM))[tid] = a4;
  if (tid == 0) out[1048576 + b] = (float)tops[0];
  if (tid < 16) {
    out[1048576 + 1024 + b * 16 + tid] = (float)topi[tid];
    out[1048576 + 1024 + 16384 + b * 16 + tid] = (float)tops[tid];
  }
}

extern "C" void kernel_launch(void* const* d_in, const int* in_sizes, int n_in,
                              void* d_out, int out_size, void* d_ws,
                              size_t ws_size, hipStream_t stream) {
  const float* qc = (const float*)d_in[0];
  const float* pat = (const float*)d_in[1];
  const float* comp = (const float*)d_in[2];
  char* ws = (char*)d_ws;
  unsigned short* pnh = (unsigned short*)(ws + 0);                    // 128 MB
  __half* sims = (__half*)(ws + 134217728);                          // 128 MB
  unsigned short* qnh = (unsigned short*)(ws + 268435456);           // 2 MB
  float* invp = (float*)(ws + 270532608);                            // 256 KB
  float* invq = (float*)(ws + 270794752);                            // 4 KB
  int* cidx = (int*)(ws + 270798848);                                // 2 MB
  int* ccnt = (int*)(ws + 272896000);                                // 4 KB
  float* out = (float*)d_out;

  k_rownorm<<<C_P / 4, 256, 0, stream>>>(pat, pnh, invp, C_P);
  k_rownorm<<<B_Q / 4, 256, 0, stream>>>(qc, qnh, invq, B_Q);
  dim3 g2(C_P / 128, B_Q / 128);
  k_gemm<<<g2, 256, 0, stream>>>(qnh, pnh, sims);
  k_cand<<<B_Q, 256, 0, stream>>>(sims, cidx, ccnt);
  k_final<<<B_Q, 256, 0, stream>>>(qc, pat, comp, invq, invp, cidx, ccnt, out);
}

// Round 2
// 417.854 us; speedup vs baseline: 2.0774x; 2.0774x over previous
//
#include <hip/hip_runtime.h>
#include <hip/hip_fp16.h>

#define B_Q 1024
#define C_P 65536
#define D_DIM 1024
#define CAND_CAP 512
#define CAND_TARGET 32

typedef __bf16 bf16x8 __attribute__((ext_vector_type(8)));
typedef float f32x4 __attribute__((ext_vector_type(4)));

__device__ __forceinline__ unsigned short f2bf(float f) {
  unsigned int u = __float_as_uint(f);
  u += 0x7FFFu + ((u >> 16) & 1u);
  return (unsigned short)(u >> 16);
}

// Async global->LDS, 16B per lane. LDS dest is wave-uniform base + lane*16.
__device__ __forceinline__ void gload_lds16(const void* gsrc, void* lds_dst) {
  __builtin_amdgcn_global_load_lds(
      (const __attribute__((address_space(1))) unsigned int*)gsrc,
      (__attribute__((address_space(3))) unsigned int*)lds_dst, 16, 0, 0);
}

// ---------------- K1: row L2-normalize -> bf16 copy + inverse norms ----------
__global__ __launch_bounds__(256) void k_rownorm(
    const float* __restrict__ src, unsigned short* __restrict__ dst,
    float* __restrict__ inv_out, int nrows) {
  const int lane = threadIdx.x & 63;
  const int wave = threadIdx.x >> 6;
  const int row = blockIdx.x * 4 + wave;
  if (row >= nrows) return;
  const float4* r4 = (const float4*)(src + (size_t)row * D_DIM);
  float4 v[4];
  float ss = 0.f;
#pragma unroll
  for (int j = 0; j < 4; ++j) {
    v[j] = r4[lane + j * 64];
    ss += v[j].x * v[j].x + v[j].y * v[j].y + v[j].z * v[j].z + v[j].w * v[j].w;
  }
#pragma unroll
  for (int off = 32; off; off >>= 1) ss += __shfl_xor(ss, off);
  const float inv = 1.0f / fmaxf(sqrtf(ss), 1e-8f);
  if (lane == 0) inv_out[row] = inv;
  ushort4* d4 = (ushort4*)(dst + (size_t)row * D_DIM);
#pragma unroll
  for (int j = 0; j < 4; ++j) {
    ushort4 h;
    h.x = f2bf(v[j].x * inv);
    h.y = f2bf(v[j].y * inv);
    h.z = f2bf(v[j].z * inv);
    h.w = f2bf(v[j].w * inv);
    d4[lane + j * 64] = h;
  }
}

// ---------------- K2: bf16 GEMM (m97 structure)  sims[b,c] = qn.pn ----------
__global__ __launch_bounds__(256) void k_gemm(
    const unsigned short* __restrict__ qnh,
    const unsigned short* __restrict__ pnh,
    __half* __restrict__ sims) {
  __shared__ unsigned short As[128 * 64];  // linear: row stride 64 (128B)
  __shared__ unsigned short Bs[128 * 64];
  const int tid = threadIdx.x;
  const int lane = tid & 63;
  const int wave = tid >> 6;
  const int wr = wave >> 1, wc = wave & 1;
  const int bCol = blockIdx.x * 128;  // pattern block
  const int bRow = blockIdx.y * 128;  // query block

  // Staging: wave w owns rows [w*32, w*32+32). One global_load_lds covers
  // 8 rows (64 lanes x 16B = 1024B). Lane l -> row +(l>>3), col (l&7)*8.
  const int srow0 = wave * 32 + (lane >> 3);
  const int scol = (lane & 7) * 8;
  const unsigned short* Ag = qnh + (size_t)(bRow + srow0) * D_DIM + scol;
  const unsigned short* Bg = pnh + (size_t)(bCol + srow0) * D_DIM + scol;
  unsigned short* Asl = &As[wave * 32 * 64];
  unsigned short* Bsl = &Bs[wave * 32 * 64];

  f32x4 zv = {0.f, 0.f, 0.f, 0.f};
  f32x4 acc[4][4];
#pragma unroll
  for (int m = 0; m < 4; ++m)
#pragma unroll
    for (int n = 0; n < 4; ++n) acc[m][n] = zv;

  for (int t = 0; t < 16; ++t) {
    __syncthreads();  // previous compute done before overwrite
#pragma unroll
    for (int i = 0; i < 4; ++i) {
      gload_lds16(Ag + (size_t)(i * 8) * D_DIM + t * 64, Asl + i * 8 * 64);
      gload_lds16(Bg + (size_t)(i * 8) * D_DIM + t * 64, Bsl + i * 8 * 64);
    }
    __syncthreads();  // compiler inserts vmcnt(0) drain before barrier
    const int rr = lane & 15;
#pragma unroll
    for (int kk = 0; kk < 2; ++kk) {
      const int ko = kk * 32 + (lane >> 4) * 8;
      bf16x8 af[4], bfr[4];
#pragma unroll
      for (int m = 0; m < 4; ++m) {
        af[m] = *(const bf16x8*)&As[(wr * 64 + m * 16 + rr) * 64 + ko];
        bfr[m] = *(const bf16x8*)&Bs[(wc * 64 + m * 16 + rr) * 64 + ko];
      }
#pragma unroll
      for (int m = 0; m < 4; ++m)
#pragma unroll
        for (int n = 0; n < 4; ++n)
          acc[m][n] = __builtin_amdgcn_mfma_f32_16x16x32_bf16(af[m], bfr[n],
                                                              acc[m][n], 0, 0, 0);
    }
  }

  const int pcol0 = bCol + wc * 64 + (lane & 15);
  const int qrow0 = bRow + wr * 64 + ((lane >> 4) << 2);
#pragma unroll
  for (int m = 0; m < 4; ++m)
#pragma unroll
    for (int n = 0; n < 4; ++n)
#pragma unroll
      for (int r = 0; r < 4; ++r)
        sims[(size_t)(qrow0 + m * 16 + r) * C_P + (pcol0 + n * 16)] =
            __float2half(acc[m][n][r]);
}

// ---------------- K3: per-query adaptive top-candidate selection -------------
__device__ __forceinline__ unsigned int h2key(unsigned int h) {
  return (h & 0x8000u) ? (0xFFFFu ^ h) : (h | 0x8000u);
}

__global__ __launch_bounds__(256) void k_cand(
    const __half* __restrict__ sims, int* __restrict__ cand_idx,
    int* __restrict__ cand_cnt) {
  const int b = blockIdx.x;
  const int tid = threadIdx.x;
  __shared__ unsigned int hist[2048];
  __shared__ int s_cnt;
  __shared__ int s_thr;
  __shared__ int cbuf[CAND_CAP];
  for (int i = tid; i < 2048; i += 256) hist[i] = 0;
  if (tid == 0) s_cnt = 0;
  __syncthreads();
  const unsigned int* row = (const unsigned int*)(sims + (size_t)b * C_P);
  for (int i = tid; i < C_P / 2; i += 256) {
    unsigned int u = row[i];
    atomicAdd(&hist[h2key(u & 0xFFFFu) >> 5], 1u);
    atomicAdd(&hist[h2key(u >> 16) >> 5], 1u);
  }
  __syncthreads();
  if (tid < 64) {  // wave 0: descending chunked suffix scan for threshold bin
    const int lane = tid;
    int cum = 0, thr = -1;
    for (int base = 2048 - 64; base >= 0; base -= 64) {
      int v = (int)hist[base + lane];
      int s = v;
#pragma unroll
      for (int off = 1; off < 64; off <<= 1) {
        int t2 = __shfl_down(s, off);
        if (lane + off < 64) s += t2;
      }
      int total = __shfl(s, 0);
      if (cum + total >= CAND_TARGET) {
        unsigned long long mb = __ballot(cum + s >= CAND_TARGET);
        thr = base + (63 - __clzll(mb));
        break;
      }
      cum += total;
    }
    if (lane == 0) s_thr = thr;
  }
  __syncthreads();
  const unsigned int thrkey = ((unsigned int)s_thr) << 5;
  for (int i = tid; i < C_P / 2; i += 256) {
    unsigned int u = row[i];
    if (h2key(u & 0xFFFFu) >= thrkey) {
      int p = atomicAdd(&s_cnt, 1);
      if (p < CAND_CAP) cbuf[p] = i * 2;
    }
    if (h2key(u >> 16) >= thrkey) {
      int p = atomicAdd(&s_cnt, 1);
      if (p < CAND_CAP) cbuf[p] = i * 2 + 1;
    }
  }
  __syncthreads();
  int cnt = s_cnt;
  if (cnt > CAND_CAP) cnt = CAND_CAP;
  if (tid == 0) cand_cnt[b] = cnt;
  for (int i = tid; i < cnt; i += 256) cand_idx[b * CAND_CAP + i] = cbuf[i];
}

// ---------------- K4: f64 refine, exact top-16, softmax, outputs -------------
__global__ __launch_bounds__(256) void k_final(
    const float* __restrict__ qc, const float* __restrict__ pat,
    const float* __restrict__ comp, const float* __restrict__ invq,
    const float* __restrict__ invp, const int* __restrict__ cand_idx,
    const int* __restrict__ cand_cnt, float* __restrict__ out) {
  const int b = blockIdx.x;
  const int tid = threadIdx.x;
  const int lane = tid & 63;
  const int wave = tid >> 6;
  __shared__ float qs[1024];
  __shared__ double sv[CAND_CAP];
  __shared__ int ci[CAND_CAP];
  __shared__ int topi[16];
  __shared__ double tops[16];
  __shared__ float wgt[16];
  const int cnt = cand_cnt[b];
  for (int i = tid; i < cnt; i += 256) ci[i] = cand_idx[b * CAND_CAP + i];
  ((float4*)qs)[tid] = ((const float4*)(qc + (size_t)b * D_DIM))[tid];
  __syncthreads();
  const double sq = (double)invq[b];
  for (int i = wave; i < cnt; i += 4) {
    const float4* p4 = (const float4*)(pat + (size_t)ci[i] * D_DIM);
    const float4* q4 = (const float4*)qs;
    double acc = 0.0;
#pragma unroll
    for (int j = 0; j < 4; ++j) {
      float4 p = p4[lane + j * 64];
      float4 q = q4[lane + j * 64];
      acc += (double)p.x * q.x + (double)p.y * q.y + (double)p.z * q.z +
             (double)p.w * q.w;
    }
#pragma unroll
    for (int off = 32; off; off >>= 1) acc += __shfl_xor(acc, off);
    if (lane == 0) sv[i] = acc * sq * (double)invp[ci[i]];
  }
  __syncthreads();
  if (wave == 0) {
    for (int k = 0; k < 16; ++k) {
      double bs = -1e300;
      int bi = 0x7FFFFFFF, bslot = -1;
      for (int s = lane; s < cnt; s += 64) {
        double d = sv[s];
        int id = ci[s];
        if (d > bs || (d == bs && id < bi)) { bs = d; bi = id; bslot = s; }
      }
#pragma unroll
      for (int off = 32; off; off >>= 1) {
        double ds = __shfl_xor(bs, off);
        int di = __shfl_xor(bi, off);
        int dsl = __shfl_xor(bslot, off);
        if (ds > bs || (ds == bs && di < bi)) { bs = ds; bi = di; bslot = dsl; }
      }
      if (lane == 0) {
        topi[k] = bi;
        tops[k] = bs;
        if (bslot >= 0) sv[bslot] = -1e301;  // remove winner
      }
    }
    if (lane < 16) {
      float ts = (float)tops[lane];
      wgt[lane] = ts * (1.0f + comp[topi[lane]]);
    }
  }
  __syncthreads();
  if (tid == 0) {  // softmax over 16
    float m = wgt[0];
    for (int k = 1; k < 16; ++k) m = fmaxf(m, wgt[k]);
    float e[16];
    float ssum = 0.f;
    for (int k = 0; k < 16; ++k) {
      e[k] = expf(wgt[k] - m);
      ssum += e[k];
    }
    for (int k = 0; k < 16; ++k) wgt[k] = e[k] / ssum;
  }
  __syncthreads();
  float4 a4 = {0.f, 0.f, 0.f, 0.f};
  for (int k = 0; k < 16; ++k) {
    float4 pv = ((const float4*)(pat + (size_t)topi[k] * D_DIM))[tid];
    const float w = wgt[k];
    a4.x += w * pv.x;
    a4.y += w * pv.y;
    a4.z += w * pv.z;
    a4.w += w * pv.w;
  }
  ((float4*)(out + (size_t)b * D_DIM))[tid] = a4;
  if (tid == 0) out[1048576 + b] = (float)tops[0];
  if (tid < 16) {
    out[1048576 + 1024 + b * 16 + tid] = (float)topi[tid];
    out[1048576 + 1024 + 16384 + b * 16 + tid] = (float)tops[tid];
  }
}

extern "C" void kernel_launch(void* const* d_in, const int* in_sizes, int n_in,
                              void* d_out, int out_size, void* d_ws,
                              size_t ws_size, hipStream_t stream) {
  const float* qc = (const float*)d_in[0];
  const float* pat = (const float*)d_in[1];
  const float* comp = (const float*)d_in[2];
  char* ws = (char*)d_ws;
  unsigned short* pnh = (unsigned short*)(ws + 0);                    // 128 MB
  __half* sims = (__half*)(ws + 134217728);                          // 128 MB
  unsigned short* qnh = (unsigned short*)(ws + 268435456);           // 2 MB
  float* invp = (float*)(ws + 270532608);                            // 256 KB
  float* invq = (float*)(ws + 270794752);                            // 4 KB
  int* cidx = (int*)(ws + 270798848);                                // 2 MB
  int* ccnt = (int*)(ws + 272896000);                                // 4 KB
  float* out = (float*)d_out;

  k_rownorm<<<C_P / 4, 256, 0, stream>>>(pat, pnh, invp, C_P);
  k_rownorm<<<B_Q / 4, 256, 0, stream>>>(qc, qnh, invq, B_Q);
  dim3 g2(C_P / 128, B_Q / 128);
  k_gemm<<<g2, 256, 0, stream>>>(qnh, pnh, sims);
  k_cand<<<B_Q, 256, 0, stream>>>(sims, cidx, ccnt);
  k_final<<<B_Q, 256, 0, stream>>>(qc, pat, comp, invq, invp, cidx, ccnt, out);
}

// Round 3
// 377.598 us; speedup vs baseline: 2.2989x; 1.1066x over previous
//
#include <hip/hip_runtime.h>
#include <hip/hip_fp16.h>

#define B_Q 1024
#define C_P 65536
#define D_DIM 1024
#define CAND_CAP 512
#define CAND_TARGET 32
#define BM 256
#define BN 256
#define BK 64

typedef __bf16 bf16x8 __attribute__((ext_vector_type(8)));
typedef float f32x4 __attribute__((ext_vector_type(4)));

__device__ __forceinline__ unsigned short f2bf(float f) {
  unsigned int u = __float_as_uint(f);
  u += 0x7FFFu + ((u >> 16) & 1u);
  return (unsigned short)(u >> 16);
}

// Async global->LDS, 16B per lane. LDS dest = wave-uniform base + lane*16.
__device__ __forceinline__ void gload16(const unsigned short* g,
                                        unsigned short* l) {
  __builtin_amdgcn_global_load_lds(
      (const __attribute__((address_space(1))) unsigned int*)g,
      (__attribute__((address_space(3))) unsigned int*)l, 16, 0, 0);
}

// ---------------- K1: row L2-normalize -> bf16 copy + inverse norms ----------
__global__ __launch_bounds__(256) void k_rownorm(
    const float* __restrict__ src, unsigned short* __restrict__ dst,
    float* __restrict__ inv_out, int nrows) {
  const int lane = threadIdx.x & 63;
  const int wave = threadIdx.x >> 6;
  const int row = blockIdx.x * 4 + wave;
  if (row >= nrows) return;
  const float4* r4 = (const float4*)(src + (size_t)row * D_DIM);
  float4 v[4];
  float ss = 0.f;
#pragma unroll
  for (int j = 0; j < 4; ++j) {
    v[j] = r4[lane + j * 64];
    ss += v[j].x * v[j].x + v[j].y * v[j].y + v[j].z * v[j].z + v[j].w * v[j].w;
  }
#pragma unroll
  for (int off = 32; off; off >>= 1) ss += __shfl_xor(ss, off);
  const float inv = 1.0f / fmaxf(sqrtf(ss), 1e-8f);
  if (lane == 0) inv_out[row] = inv;
  ushort4* d4 = (ushort4*)(dst + (size_t)row * D_DIM);
#pragma unroll
  for (int j = 0; j < 4; ++j) {
    ushort4 h;
    h.x = f2bf(v[j].x * inv);
    h.y = f2bf(v[j].y * inv);
    h.z = f2bf(v[j].z * inv);
    h.w = f2bf(v[j].w * inv);
    d4[lane + j * 64] = h;
  }
}

// ---------------- K2: bf16 GEMM, 256x256 tile, 8-phase counted-vmcnt --------
// 8 waves (2M x 4N); per-wave output 128x64 (8x4 fragments of 16x16).
// LDS: 2 dbuf x (A 32KB + B 32KB) = 128KB. Staged via global_load_lds with
// pre-swizzled global source: phys slot s holds logical slot s^(row&7).
// Reads XOR the same way -> 16-way bank conflict becomes ~2-way (free).
// vmcnt(2) only at phases 4/8; derived issue-windows/deadlines per chunk.
#define STG_A(buf, R0, t) \
  gload16(pAg + (size_t)(R0)*D_DIM + (t)*BK, &As[buf][(R0)*64 + wave * 512])
#define STG_B(buf, R0, t) \
  gload16(pBg + (size_t)(R0)*D_DIM + (t)*BK, &Bs[buf][(R0)*64 + wave * 512])

#define RD_A(buf, mbase)                                                    \
  _Pragma("unroll") for (int m = 0; m < 4; ++m) {                           \
    _Pragma("unroll") for (int kk = 0; kk < 2; ++kk) {                      \
      const int r_ = wm * 128 + ((mbase) + m) * 16 + rr;                    \
      const int sl_ = (kk * 4 + klane) ^ l7;                                \
      af[m * 2 + kk] = *(const bf16x8*)&As[buf][r_ * 64 + sl_ * 8];         \
    }                                                                       \
  }

#define RD_B(dst, buf, nbase)                                               \
  _Pragma("unroll") for (int n = 0; n < 2; ++n) {                           \
    _Pragma("unroll") for (int kk = 0; kk < 2; ++kk) {                      \
      const int r_ = wn * 64 + ((nbase) + n) * 16 + rr;                     \
      const int sl_ = (kk * 4 + klane) ^ l7;                                \
      dst[n * 2 + kk] = *(const bf16x8*)&Bs[buf][r_ * 64 + sl_ * 8];        \
    }                                                                       \
  }

#define MM(mbase, nbase, bsrc)                                              \
  _Pragma("unroll") for (int m = 0; m < 4; ++m) {                           \
    _Pragma("unroll") for (int n = 0; n < 2; ++n) {                         \
      _Pragma("unroll") for (int kk = 0; kk < 2; ++kk) {                    \
        acc[(mbase) + m][(nbase) + n] =                                     \
            __builtin_amdgcn_mfma_f32_16x16x32_bf16(                        \
                af[m * 2 + kk], bsrc[n * 2 + kk],                           \
                acc[(mbase) + m][(nbase) + n], 0, 0, 0);                    \
      }                                                                     \
    }                                                                       \
  }

#define FENCE asm volatile("" ::: "memory")
#define BAR                         \
  do {                              \
    FENCE;                          \
    __builtin_amdgcn_s_barrier();   \
    FENCE;                          \
  } while (0)
#define VMC(n) asm volatile("s_waitcnt vmcnt(" #n ")" ::: "memory")
#define SP1 __builtin_amdgcn_s_setprio(1)
#define SP0 __builtin_amdgcn_s_setprio(0)

__global__ __launch_bounds__(512, 2) void k_gemm(
    const unsigned short* __restrict__ qnh,
    const unsigned short* __restrict__ pnh, __half* __restrict__ sims) {
  __shared__ __align__(16) unsigned short As[2][BM * BK];
  __shared__ __align__(16) unsigned short Bs[2][BN * BK];
  const int tid = threadIdx.x;
  const int lane = tid & 63;
  const int wave = tid >> 6;
  const int wm = wave >> 2;  // 0..1
  const int wn = wave & 3;   // 0..3
  const int bCol = blockIdx.x * BN;
  const int bRow = blockIdx.y * BM;
  const int rr = lane & 15;
  const int klane = lane >> 4;
  const int l7 = lane & 7;

  // Staging source: thread tid covers row (R0 + tid>>3), pre-swizzled col.
  const int srow = tid >> 3;
  const int scol = ((tid & 7) ^ ((tid >> 3) & 7)) * 8;
  const unsigned short* pAg = qnh + (size_t)(bRow + srow) * D_DIM + scol;
  const unsigned short* pBg = pnh + (size_t)(bCol + srow) * D_DIM + scol;

  f32x4 acc[8][4];
#pragma unroll
  for (int m = 0; m < 8; ++m)
#pragma unroll
    for (int n = 0; n < 4; ++n) acc[m][n] = (f32x4){0.f, 0.f, 0.f, 0.f};
  bf16x8 af[8], blo[4], bhi[4];

  // Prologue: tile0 full (A,B) + tile1 A q0,q2. Leaves last 2 in flight.
  STG_A(0, 0, 0); STG_A(0, 64, 0); STG_A(0, 128, 0); STG_A(0, 192, 0);
  STG_B(0, 0, 0); STG_B(0, 64, 0); STG_B(0, 128, 0); STG_B(0, 192, 0);
  STG_A(1, 0, 1); STG_A(1, 128, 1);
  VMC(2);
  BAR;

  for (int i = 0; i < 8; ++i) {
    const int T1 = 2 * i + 1, T2 = 2 * i + 2, T3 = 2 * i + 3;
    const bool st = (i < 7);
    // ---- P1: Q0 of tile 2i (buf0) ----
    RD_A(0, 0);
    RD_B(blo, 0, 0);
    STG_B(1, 0, T1); STG_B(1, 64, T1);
    BAR; SP1; MM(0, 0, blo); SP0; BAR;
    // ---- P2: Q1 ----
    RD_B(bhi, 0, 2);
    STG_B(1, 128, T1); STG_B(1, 192, T1);
    BAR; SP1; MM(0, 2, bhi); SP0; BAR;
    // ---- P3: Q2 ----
    RD_A(0, 4);
    STG_A(1, 64, T1); STG_A(1, 192, T1);
    BAR; SP1; MM(4, 0, blo); SP0; BAR;
    // ---- P4: Q3 + K-tile boundary checkpoint ----
    if (st) { STG_A(0, 0, T2); STG_A(0, 128, T2); }
    BAR; SP1; MM(4, 2, bhi); SP0;
    if (st) { VMC(2); } else { VMC(0); }
    BAR;
    // ---- P5: Q0 of tile 2i+1 (buf1) ----
    RD_A(1, 0);
    RD_B(blo, 1, 0);
    if (st) { STG_A(0, 64, T2); STG_A(0, 192, T2); }
    BAR; SP1; MM(0, 0, blo); SP0; BAR;
    // ---- P6: Q1 ----
    RD_B(bhi, 1, 2);
    if (st) { STG_B(0, 0, T2); STG_B(0, 64, T2); }
    BAR; SP1; MM(0, 2, bhi); SP0; BAR;
    // ---- P7: Q2 ----
    RD_A(1, 4);
    if (st) { STG_B(0, 128, T2); STG_B(0, 192, T2); }
    BAR; SP1; MM(4, 0, blo); SP0; BAR;
    // ---- P8: Q3 + boundary checkpoint ----
    if (st) { STG_A(1, 0, T3); STG_A(1, 128, T3); }
    BAR; SP1; MM(4, 2, bhi); SP0;
    if (st) { VMC(2); } else { VMC(0); }
    BAR;
  }

  // Epilogue: C write (fp16 sims)
#pragma unroll
  for (int m = 0; m < 8; ++m)
#pragma unroll
    for (int n = 0; n < 4; ++n)
#pragma unroll
      for (int r = 0; r < 4; ++r)
        sims[(size_t)(bRow + wm * 128 + m * 16 + klane * 4 + r) * C_P +
             (bCol + wn * 64 + n * 16 + rr)] = __float2half(acc[m][n][r]);
}

// ---------------- K3: per-query adaptive top-candidate selection -------------
__device__ __forceinline__ unsigned int h2key(unsigned int h) {
  return (h & 0x8000u) ? (0xFFFFu ^ h) : (h | 0x8000u);
}

__global__ __launch_bounds__(256) void k_cand(
    const __half* __restrict__ sims, int* __restrict__ cand_idx,
    int* __restrict__ cand_cnt) {
  const int b = blockIdx.x;
  const int tid = threadIdx.x;
  __shared__ unsigned int hist[2048];
  __shared__ int s_cnt;
  __shared__ int s_thr;
  __shared__ int cbuf[CAND_CAP];
  for (int i = tid; i < 2048; i += 256) hist[i] = 0;
  if (tid == 0) s_cnt = 0;
  __syncthreads();
  const unsigned int* row = (const unsigned int*)(sims + (size_t)b * C_P);
  for (int i = tid; i < C_P / 2; i += 256) {
    unsigned int u = row[i];
    atomicAdd(&hist[h2key(u & 0xFFFFu) >> 5], 1u);
    atomicAdd(&hist[h2key(u >> 16) >> 5], 1u);
  }
  __syncthreads();
  if (tid < 64) {  // wave 0: descending chunked suffix scan for threshold bin
    const int lane = tid;
    int cum = 0, thr = -1;
    for (int base = 2048 - 64; base >= 0; base -= 64) {
      int v = (int)hist[base + lane];
      int s = v;
#pragma unroll
      for (int off = 1; off < 64; off <<= 1) {
        int t2 = __shfl_down(s, off);
        if (lane + off < 64) s += t2;
      }
      int total = __shfl(s, 0);
      if (cum + total >= CAND_TARGET) {
        unsigned long long mb = __ballot(cum + s >= CAND_TARGET);
        thr = base + (63 - __clzll(mb));
        break;
      }
      cum += total;
    }
    if (lane == 0) s_thr = thr;
  }
  __syncthreads();
  const unsigned int thrkey = ((unsigned int)s_thr) << 5;
  for (int i = tid; i < C_P / 2; i += 256) {
    unsigned int u = row[i];
    if (h2key(u & 0xFFFFu) >= thrkey) {
      int p = atomicAdd(&s_cnt, 1);
      if (p < CAND_CAP) cbuf[p] = i * 2;
    }
    if (h2key(u >> 16) >= thrkey) {
      int p = atomicAdd(&s_cnt, 1);
      if (p < CAND_CAP) cbuf[p] = i * 2 + 1;
    }
  }
  __syncthreads();
  int cnt = s_cnt;
  if (cnt > CAND_CAP) cnt = CAND_CAP;
  if (tid == 0) cand_cnt[b] = cnt;
  for (int i = tid; i < cnt; i += 256) cand_idx[b * CAND_CAP + i] = cbuf[i];
}

// ---------------- K4: f64 refine, exact top-16, softmax, outputs -------------
__global__ __launch_bounds__(256) void k_final(
    const float* __restrict__ qc, const float* __restrict__ pat,
    const float* __restrict__ comp, const float* __restrict__ invq,
    const float* __restrict__ invp, const int* __restrict__ cand_idx,
    const int* __restrict__ cand_cnt, float* __restrict__ out) {
  const int b = blockIdx.x;
  const int tid = threadIdx.x;
  const int lane = tid & 63;
  const int wave = tid >> 6;
  __shared__ float qs[1024];
  __shared__ double sv[CAND_CAP];
  __shared__ int ci[CAND_CAP];
  __shared__ int topi[16];
  __shared__ double tops[16];
  __shared__ float wgt[16];
  const int cnt = cand_cnt[b];
  for (int i = tid; i < cnt; i += 256) ci[i] = cand_idx[b * CAND_CAP + i];
  ((float4*)qs)[tid] = ((const float4*)(qc + (size_t)b * D_DIM))[tid];
  __syncthreads();
  const double sq = (double)invq[b];
  for (int i = wave; i < cnt; i += 4) {
    const float4* p4 = (const float4*)(pat + (size_t)ci[i] * D_DIM);
    const float4* q4 = (const float4*)qs;
    double acc = 0.0;
#pragma unroll
    for (int j = 0; j < 4; ++j) {
      float4 p = p4[lane + j * 64];
      float4 q = q4[lane + j * 64];
      acc += (double)p.x * q.x + (double)p.y * q.y + (double)p.z * q.z +
             (double)p.w * q.w;
    }
#pragma unroll
    for (int off = 32; off; off >>= 1) acc += __shfl_xor(acc, off);
    if (lane == 0) sv[i] = acc * sq * (double)invp[ci[i]];
  }
  __syncthreads();
  if (wave == 0) {
    for (int k = 0; k < 16; ++k) {
      double bs = -1e300;
      int bi = 0x7FFFFFFF, bslot = -1;
      for (int s = lane; s < cnt; s += 64) {
        double d = sv[s];
        int id = ci[s];
        if (d > bs || (d == bs && id < bi)) { bs = d; bi = id; bslot = s; }
      }
#pragma unroll
      for (int off = 32; off; off >>= 1) {
        double ds = __shfl_xor(bs, off);
        int di = __shfl_xor(bi, off);
        int dsl = __shfl_xor(bslot, off);
        if (ds > bs || (ds == bs && di < bi)) { bs = ds; bi = di; bslot = dsl; }
      }
      if (lane == 0) {
        topi[k] = bi;
        tops[k] = bs;
        if (bslot >= 0) sv[bslot] = -1e301;  // remove winner
      }
    }
    if (lane < 16) {
      float ts = (float)tops[lane];
      wgt[lane] = ts * (1.0f + comp[topi[lane]]);
    }
  }
  __syncthreads();
  if (tid == 0) {  // softmax over 16
    float m = wgt[0];
    for (int k = 1; k < 16; ++k) m = fmaxf(m, wgt[k]);
    float e[16];
    float ssum = 0.f;
    for (int k = 0; k < 16; ++k) {
      e[k] = expf(wgt[k] - m);
      ssum += e[k];
    }
    for (int k = 0; k < 16; ++k) wgt[k] = e[k] / ssum;
  }
  __syncthreads();
  float4 a4 = {0.f, 0.f, 0.f, 0.f};
  for (int k = 0; k < 16; ++k) {
    float4 pv = ((const float4*)(pat + (size_t)topi[k] * D_DIM))[tid];
    const float w = wgt[k];
    a4.x += w * pv.x;
    a4.y += w * pv.y;
    a4.z += w * pv.z;
    a4.w += w * pv.w;
  }
  ((float4*)(out + (size_t)b * D_DIM))[tid] = a4;
  if (tid == 0) out[1048576 + b] = (float)tops[0];
  if (tid < 16) {
    out[1048576 + 1024 + b * 16 + tid] = (float)topi[tid];
    out[1048576 + 1024 + 16384 + b * 16 + tid] = (float)tops[tid];
  }
}

extern "C" void kernel_launch(void* const* d_in, const int* in_sizes, int n_in,
                              void* d_out, int out_size, void* d_ws,
                              size_t ws_size, hipStream_t stream) {
  const float* qc = (const float*)d_in[0];
  const float* pat = (const float*)d_in[1];
  const float* comp = (const float*)d_in[2];
  char* ws = (char*)d_ws;
  unsigned short* pnh = (unsigned short*)(ws + 0);                    // 128 MB
  __half* sims = (__half*)(ws + 134217728);                          // 128 MB
  unsigned short* qnh = (unsigned short*)(ws + 268435456);           // 2 MB
  float* invp = (float*)(ws + 270532608);                            // 256 KB
  float* invq = (float*)(ws + 270794752);                            // 4 KB
  int* cidx = (int*)(ws + 270798848);                                // 2 MB
  int* ccnt = (int*)(ws + 272896000);                                // 4 KB
  float* out = (float*)d_out;

  k_rownorm<<<C_P / 4, 256, 0, stream>>>(pat, pnh, invp, C_P);
  k_rownorm<<<B_Q / 4, 256, 0, stream>>>(qc, qnh, invq, B_Q);
  dim3 g2(C_P / BN, B_Q / BM);
  k_gemm<<<g2, 512, 0, stream>>>(qnh, pnh, sims);
  k_cand<<<B_Q, 256, 0, stream>>>(sims, cidx, ccnt);
  k_final<<<B_Q, 256, 0, stream>>>(qc, pat, comp, invq, invp, cidx, ccnt, out);
}